// Round 1
// baseline (98.082 us; speedup 1.0000x reference)
//
#include <hip/hip_runtime.h>
#include <cstdint>

#define NV 200000
#define NCOLS 5
#define P 128
#define NE 8192

__global__ __launch_bounds__(256) void clust_geo_edge_kernel(
    const float* __restrict__ data,
    const int*   __restrict__ clusts,
    const int*   __restrict__ edge_index,
    float*       __restrict__ out)
{
    const int e = blockIdx.x;
    const int t = threadIdx.x;

    __shared__ float x1s[P][3];
    __shared__ float x2s[P][3];
    __shared__ unsigned long long wmin[4];

    const int c1 = edge_index[e];
    const int c2 = edge_index[NE + e];

    // Stage both clusters' coords (data cols 1..3) into LDS.
    if (t < P) {
        const int v = clusts[c1 * P + t];
        x1s[t][0] = data[v * NCOLS + 1];
        x1s[t][1] = data[v * NCOLS + 2];
        x1s[t][2] = data[v * NCOLS + 3];
    } else {
        const int p = t - P;
        const int v = clusts[c2 * P + p];
        x2s[p][0] = data[v * NCOLS + 1];
        x2s[p][1] = data[v * NCOLS + 2];
        x2s[p][2] = data[v * NCOLS + 3];
    }
    __syncthreads();

    // Thread t owns flat pairs [t*64, t*64+64): i = t>>1 fixed, j = (t&1)*64 + k.
    const int i  = t >> 1;
    const int j0 = (t & 1) * 64;
    const float ax = x1s[i][0], ay = x1s[i][1], az = x1s[i][2];

    float bestd = __builtin_inff();
    int   bestflat = i * P + j0;

    // Exact replication of reference fp32 arithmetic: (dx*dx + dy*dy) + dz*dz,
    // no FMA contraction (argmin tie-breaking must match numpy).
    #pragma unroll 8
    for (int k = 0; k < 64; ++k) {
        const int j = j0 + k;
        const float dx = __fsub_rn(ax, x2s[j][0]);
        const float dy = __fsub_rn(ay, x2s[j][1]);
        const float dz = __fsub_rn(az, x2s[j][2]);
        const float d2 = __fadd_rn(__fadd_rn(__fmul_rn(dx, dx), __fmul_rn(dy, dy)),
                                   __fmul_rn(dz, dz));
        if (d2 < bestd) { bestd = d2; bestflat = i * P + j; }  // strict < keeps first (smallest j)
    }

    // Pack (d2, flat) into one 64-bit key: d2 >= 0 so float bits are monotone.
    // min(key) == (min d2, then min flat) — matches jnp.argmin tie-break.
    unsigned long long key =
        ((unsigned long long)__float_as_uint(bestd) << 32) | (unsigned)bestflat;

    // Wave-level (64-lane) min reduce.
    for (int off = 32; off > 0; off >>= 1) {
        unsigned long long other = __shfl_down(key, off, 64);
        if (other < key) key = other;
    }
    const int wave = t >> 6;
    if ((t & 63) == 0) wmin[wave] = key;
    __syncthreads();

    if (t == 0) {
        unsigned long long k0 = wmin[0];
        #pragma unroll
        for (int w = 1; w < 4; ++w) if (wmin[w] < k0) k0 = wmin[w];
        const int flat = (int)(k0 & 0xffffffffull);
        const int i1 = flat >> 7;
        const int i2 = flat & (P - 1);

        const float v1x = x1s[i1][0], v1y = x1s[i1][1], v1z = x1s[i1][2];
        const float v2x = x2s[i2][0], v2y = x2s[i2][1], v2z = x2s[i2][2];

        const float dx = v1x - v2x, dy = v1y - v2y, dz = v1z - v2z;
        const float lend = sqrtf(dx * dx + dy * dy + dz * dz);

        float nx, ny, nz;
        if (lend > 0.f) { nx = dx / lend; ny = dy / lend; nz = dz / lend; }
        else            { nx = dx;        ny = dy;        nz = dz;        }

        const float B[9] = { nx*nx, nx*ny, nx*nz,
                             ny*nx, ny*ny, ny*nz,
                             nz*nx, nz*ny, nz*nz };

        float* o = out + (size_t)e * 38;
        // feats: v1, v2, dispn, lend, B
        o[0] = v1x; o[1] = v1y; o[2] = v1z;
        o[3] = v2x; o[4] = v2y; o[5] = v2z;
        o[6] = nx;  o[7] = ny;  o[8] = nz;  o[9] = lend;
        #pragma unroll
        for (int q = 0; q < 9; ++q) o[10 + q] = B[q];
        // feats_flip: v2, v1, -dispn, lend, B
        o[19] = v2x; o[20] = v2y; o[21] = v2z;
        o[22] = v1x; o[23] = v1y; o[24] = v1z;
        o[25] = -nx; o[26] = -ny; o[27] = -nz; o[28] = lend;
        #pragma unroll
        for (int q = 0; q < 9; ++q) o[29 + q] = B[q];
    }
}

extern "C" void kernel_launch(void* const* d_in, const int* in_sizes, int n_in,
                              void* d_out, int out_size, void* d_ws, size_t ws_size,
                              hipStream_t stream) {
    const float* data       = (const float*)d_in[0];
    const int*   clusts     = (const int*)d_in[1];
    const int*   edge_index = (const int*)d_in[2];
    float*       out        = (float*)d_out;

    clust_geo_edge_kernel<<<NE, 256, 0, stream>>>(data, clusts, edge_index, out);
}

// Round 2
// 94.533 us; speedup vs baseline: 1.0375x; 1.0375x over previous
//
#include <hip/hip_runtime.h>
#include <cstdint>

#define NV 200000
#define NCOLS 5
#define P 128
#define NE 8192

__global__ __launch_bounds__(256) void clust_geo_edge_kernel(
    const float* __restrict__ data,
    const int*   __restrict__ clusts,
    const int*   __restrict__ edge_index,
    float*       __restrict__ out)
{
    const int e = blockIdx.x;
    const int t = threadIdx.x;

    // float4-padded so each point is one ds_read_b128.
    __shared__ float4 x1s[P];
    __shared__ float4 x2s[P];
    __shared__ unsigned long long wmin[4];

    const int c1 = edge_index[e];
    const int c2 = edge_index[NE + e];

    // Stage both clusters' coords (data cols 1..3) into LDS.
    if (t < P) {
        const int v = clusts[c1 * P + t];
        x1s[t] = make_float4(data[v * NCOLS + 1], data[v * NCOLS + 2],
                             data[v * NCOLS + 3], 0.f);
    } else {
        const int p = t - P;
        const int v = clusts[c2 * P + p];
        x2s[p] = make_float4(data[v * NCOLS + 1], data[v * NCOLS + 2],
                             data[v * NCOLS + 3], 0.f);
    }
    __syncthreads();

    // 16x16 thread grid over an 8x8 register tile of pairs.
    // i = ti + 16*k (k=0..7), j = tj + 16*m (m=0..7). Stride-16 rows keep
    // the b128 LDS reads at worst 2-way conflicted (free).
    const int tj = t & 15;
    const int ti = t >> 4;

    float4 a[8], b[8];
    #pragma unroll
    for (int k = 0; k < 8; ++k) a[k] = x1s[ti + 16 * k];
    #pragma unroll
    for (int m = 0; m < 8; ++m) b[m] = x2s[tj + 16 * m];

    // Per-i running best: strict < with j ascending keeps the smallest j.
    float bd[8];
    int   bj[8];
    #pragma unroll
    for (int k = 0; k < 8; ++k) { bd[k] = __builtin_inff(); bj[k] = 0; }

    // Exact replication of reference fp32 arithmetic: (dx*dx + dy*dy) + dz*dz,
    // no FMA contraction (argmin tie-breaking must match numpy).
    #pragma unroll
    for (int m = 0; m < 8; ++m) {
        const int j = tj + 16 * m;
        const float bx = b[m].x, by = b[m].y, bz = b[m].z;
        #pragma unroll
        for (int k = 0; k < 8; ++k) {
            const float dx = __fsub_rn(a[k].x, bx);
            const float dy = __fsub_rn(a[k].y, by);
            const float dz = __fsub_rn(a[k].z, bz);
            const float d2 = __fadd_rn(__fadd_rn(__fmul_rn(dx, dx), __fmul_rn(dy, dy)),
                                       __fmul_rn(dz, dz));
            if (d2 < bd[k]) { bd[k] = d2; bj[k] = j; }
        }
    }

    // Combine per-i bests with i ascending: ties keep smaller i => smaller flat.
    float bestd = __builtin_inff();
    int   bestflat = 0;
    #pragma unroll
    for (int k = 0; k < 8; ++k) {
        if (bd[k] < bestd) { bestd = bd[k]; bestflat = (ti + 16 * k) * P + bj[k]; }
    }

    // Pack (d2, flat) into one 64-bit key: d2 >= 0 so float bits are monotone.
    // min(key) == (min d2, then min flat) — matches jnp.argmin tie-break.
    unsigned long long key =
        ((unsigned long long)__float_as_uint(bestd) << 32) | (unsigned)bestflat;

    // Wave-level (64-lane) min reduce.
    for (int off = 32; off > 0; off >>= 1) {
        unsigned long long other = __shfl_down(key, off, 64);
        if (other < key) key = other;
    }
    const int wave = t >> 6;
    if ((t & 63) == 0) wmin[wave] = key;
    __syncthreads();

    if (t == 0) {
        unsigned long long k0 = wmin[0];
        #pragma unroll
        for (int w = 1; w < 4; ++w) if (wmin[w] < k0) k0 = wmin[w];
        const int flat = (int)(k0 & 0xffffffffull);
        const int i1 = flat >> 7;
        const int i2 = flat & (P - 1);

        const float v1x = x1s[i1].x, v1y = x1s[i1].y, v1z = x1s[i1].z;
        const float v2x = x2s[i2].x, v2y = x2s[i2].y, v2z = x2s[i2].z;

        const float dx = v1x - v2x, dy = v1y - v2y, dz = v1z - v2z;
        const float lend = sqrtf(dx * dx + dy * dy + dz * dz);

        float nx, ny, nz;
        if (lend > 0.f) { nx = dx / lend; ny = dy / lend; nz = dz / lend; }
        else            { nx = dx;        ny = dy;        nz = dz;        }

        const float B[9] = { nx*nx, nx*ny, nx*nz,
                             ny*nx, ny*ny, ny*nz,
                             nz*nx, nz*ny, nz*nz };

        float* o = out + (size_t)e * 38;
        // feats: v1, v2, dispn, lend, B
        o[0] = v1x; o[1] = v1y; o[2] = v1z;
        o[3] = v2x; o[4] = v2y; o[5] = v2z;
        o[6] = nx;  o[7] = ny;  o[8] = nz;  o[9] = lend;
        #pragma unroll
        for (int q = 0; q < 9; ++q) o[10 + q] = B[q];
        // feats_flip: v2, v1, -dispn, lend, B
        o[19] = v2x; o[20] = v2y; o[21] = v2z;
        o[22] = v1x; o[23] = v1y; o[24] = v1z;
        o[25] = -nx; o[26] = -ny; o[27] = -nz; o[28] = lend;
        #pragma unroll
        for (int q = 0; q < 9; ++q) o[29 + q] = B[q];
    }
}

extern "C" void kernel_launch(void* const* d_in, const int* in_sizes, int n_in,
                              void* d_out, int out_size, void* d_ws, size_t ws_size,
                              hipStream_t stream) {
    const float* data       = (const float*)d_in[0];
    const int*   clusts     = (const int*)d_in[1];
    const int*   edge_index = (const int*)d_in[2];
    float*       out        = (float*)d_out;

    clust_geo_edge_kernel<<<NE, 256, 0, stream>>>(data, clusts, edge_index, out);
}

// Round 3
// 94.320 us; speedup vs baseline: 1.0399x; 1.0023x over previous
//
#include <hip/hip_runtime.h>
#include <cstdint>

#define NV 200000
#define NCOLS 5
#define P 128
#define NE 8192
#define NC 1024

// Kernel 1: gather all clusters' coords once into dense float4 array.
// ws[c*P + p] = (data[v,1], data[v,2], data[v,3], 0) where v = clusts[c,p].
// 131072 scattered gathers (16x fewer than per-edge re-gathering).
__global__ __launch_bounds__(256) void gather_kernel(
    const float* __restrict__ data,
    const int*   __restrict__ clusts,
    float4*      __restrict__ ws)
{
    const int idx = blockIdx.x * 256 + threadIdx.x;   // 0 .. NC*P-1
    const int v = clusts[idx];
    ws[idx] = make_float4(data[v * NCOLS + 1], data[v * NCOLS + 2],
                          data[v * NCOLS + 3], 0.f);
}

template <bool USE_WS>
__global__ __launch_bounds__(256) void clust_geo_edge_kernel(
    const float*  __restrict__ data,
    const int*    __restrict__ clusts,
    const int*    __restrict__ edge_index,
    const float4* __restrict__ ws,
    float*        __restrict__ out)
{
    const int e = blockIdx.x;
    const int t = threadIdx.x;

    __shared__ float4 x1s[P];
    __shared__ float4 x2s[P];
    __shared__ unsigned long long wmin[4];

    const int c1 = edge_index[e];
    const int c2 = edge_index[NE + e];

    // Stage both clusters into LDS. With USE_WS this is one coalesced
    // dwordx4 per thread from the dense 2MB L2-resident gather array.
    if (USE_WS) {
        if (t < P) x1s[t]     = ws[c1 * P + t];
        else       x2s[t - P] = ws[c2 * P + (t - P)];
    } else {
        if (t < P) {
            const int v = clusts[c1 * P + t];
            x1s[t] = make_float4(data[v * NCOLS + 1], data[v * NCOLS + 2],
                                 data[v * NCOLS + 3], 0.f);
        } else {
            const int p = t - P;
            const int v = clusts[c2 * P + p];
            x2s[p] = make_float4(data[v * NCOLS + 1], data[v * NCOLS + 2],
                                 data[v * NCOLS + 3], 0.f);
        }
    }
    __syncthreads();

    // 16x16 thread grid over an 8x8 register tile of pairs.
    // i = ti + 16*k (k=0..7), j = tj + 16*m (m=0..7).
    const int tj = t & 15;
    const int ti = t >> 4;

    float4 a[8], b[8];
    #pragma unroll
    for (int k = 0; k < 8; ++k) a[k] = x1s[ti + 16 * k];
    #pragma unroll
    for (int m = 0; m < 8; ++m) b[m] = x2s[tj + 16 * m];

    // Per-i running best: strict < with j ascending keeps the smallest j.
    float bd[8];
    int   bj[8];
    #pragma unroll
    for (int k = 0; k < 8; ++k) { bd[k] = __builtin_inff(); bj[k] = 0; }

    // Exact replication of reference fp32 arithmetic: (dx*dx + dy*dy) + dz*dz,
    // no FMA contraction (argmin tie-breaking must match numpy).
    #pragma unroll
    for (int m = 0; m < 8; ++m) {
        const int j = tj + 16 * m;
        const float bx = b[m].x, by = b[m].y, bz = b[m].z;
        #pragma unroll
        for (int k = 0; k < 8; ++k) {
            const float dx = __fsub_rn(a[k].x, bx);
            const float dy = __fsub_rn(a[k].y, by);
            const float dz = __fsub_rn(a[k].z, bz);
            const float d2 = __fadd_rn(__fadd_rn(__fmul_rn(dx, dx), __fmul_rn(dy, dy)),
                                       __fmul_rn(dz, dz));
            if (d2 < bd[k]) { bd[k] = d2; bj[k] = j; }
        }
    }

    // Combine per-i bests with i ascending: ties keep smaller i => smaller flat.
    float bestd = __builtin_inff();
    int   bestflat = 0;
    #pragma unroll
    for (int k = 0; k < 8; ++k) {
        if (bd[k] < bestd) { bestd = bd[k]; bestflat = (ti + 16 * k) * P + bj[k]; }
    }

    // Pack (d2, flat) into one 64-bit key: d2 >= 0 so float bits are monotone.
    // min(key) == (min d2, then min flat) — matches jnp.argmin tie-break.
    unsigned long long key =
        ((unsigned long long)__float_as_uint(bestd) << 32) | (unsigned)bestflat;

    // Wave-level (64-lane) min reduce.
    for (int off = 32; off > 0; off >>= 1) {
        unsigned long long other = __shfl_down(key, off, 64);
        if (other < key) key = other;
    }
    const int wave = t >> 6;
    if ((t & 63) == 0) wmin[wave] = key;
    __syncthreads();

    if (t == 0) {
        unsigned long long k0 = wmin[0];
        #pragma unroll
        for (int w = 1; w < 4; ++w) if (wmin[w] < k0) k0 = wmin[w];
        const int flat = (int)(k0 & 0xffffffffull);
        const int i1 = flat >> 7;
        const int i2 = flat & (P - 1);

        const float v1x = x1s[i1].x, v1y = x1s[i1].y, v1z = x1s[i1].z;
        const float v2x = x2s[i2].x, v2y = x2s[i2].y, v2z = x2s[i2].z;

        const float dx = v1x - v2x, dy = v1y - v2y, dz = v1z - v2z;
        const float lend = sqrtf(dx * dx + dy * dy + dz * dz);

        float nx, ny, nz;
        if (lend > 0.f) { nx = dx / lend; ny = dy / lend; nz = dz / lend; }
        else            { nx = dx;        ny = dy;        nz = dz;        }

        const float B[9] = { nx*nx, nx*ny, nx*nz,
                             ny*nx, ny*ny, ny*nz,
                             nz*nx, nz*ny, nz*nz };

        float* o = out + (size_t)e * 38;
        // feats: v1, v2, dispn, lend, B
        o[0] = v1x; o[1] = v1y; o[2] = v1z;
        o[3] = v2x; o[4] = v2y; o[5] = v2z;
        o[6] = nx;  o[7] = ny;  o[8] = nz;  o[9] = lend;
        #pragma unroll
        for (int q = 0; q < 9; ++q) o[10 + q] = B[q];
        // feats_flip: v2, v1, -dispn, lend, B
        o[19] = v2x; o[20] = v2y; o[21] = v2z;
        o[22] = v1x; o[23] = v1y; o[24] = v1z;
        o[25] = -nx; o[26] = -ny; o[27] = -nz; o[28] = lend;
        #pragma unroll
        for (int q = 0; q < 9; ++q) o[29 + q] = B[q];
    }
}

extern "C" void kernel_launch(void* const* d_in, const int* in_sizes, int n_in,
                              void* d_out, int out_size, void* d_ws, size_t ws_size,
                              hipStream_t stream) {
    const float* data       = (const float*)d_in[0];
    const int*   clusts     = (const int*)d_in[1];
    const int*   edge_index = (const int*)d_in[2];
    float*       out        = (float*)d_out;
    float4*      ws         = (float4*)d_ws;

    const size_t need = (size_t)NC * P * sizeof(float4);  // 2 MB
    if (ws_size >= need) {
        gather_kernel<<<(NC * P) / 256, 256, 0, stream>>>(data, clusts, ws);
        clust_geo_edge_kernel<true><<<NE, 256, 0, stream>>>(data, clusts, edge_index, ws, out);
    } else {
        clust_geo_edge_kernel<false><<<NE, 256, 0, stream>>>(data, clusts, edge_index, ws, out);
    }
}